// Round 1
// baseline (246.281 us; speedup 1.0000x reference)
//
#include <hip/hip_runtime.h>
#include <math.h>

#define DD 2048
#define EE 64
#define TM 64
#define BK 64
#define NCHUNK (DD / BK)
#define THREADS 256
#define LDSTR (TM + 4)   // 68 floats: keeps 16B alignment for b128 reads

__global__ __launch_bounds__(THREADS) void router_kernel(
    const float* __restrict__ x, const float* __restrict__ W,
    const float* __restrict__ bias_g, float* __restrict__ out, int n_tokens)
{
    __shared__ float xs[BK * LDSTR];
    __shared__ float ws[BK * LDSTR];
    __shared__ float logits[TM * (EE + 1)];

    const int tid = threadIdx.x;
    const int tx  = tid & 15;   // expert group: experts tx*4 .. tx*4+3
    const int ty  = tid >> 4;   // token group:  tokens  ty*4 .. ty*4+3
    const int tBase = blockIdx.x * TM;

    const float* xg = x + (size_t)tBase * DD;

    float acc[4][4];
#pragma unroll
    for (int i = 0; i < 4; ++i)
#pragma unroll
        for (int j = 0; j < 4; ++j) acc[i][j] = 0.f;

    // bias for this thread's 4 experts
    float bvals[4];
#pragma unroll
    for (int j = 0; j < 4; ++j) bvals[j] = bias_g[tx * 4 + j];

    // prefetch registers: 4 float4 of x-tile, 4 of W-tile per chunk
    float4 rx[4], rw[4];

    // loader mapping: pass p -> row (ty + 16p), cols (tx*4 .. tx*4+3) of the
    // 64x64 chunk. Coalesced: 16 consecutive tx cover 256B of one row.
#define LOAD_TILES(k0)                                                        \
    {                                                                         \
        _Pragma("unroll")                                                     \
        for (int p = 0; p < 4; ++p) {                                         \
            rx[p] = *(const float4*)&xg[(size_t)(ty + 16 * p) * DD + (k0) + tx * 4]; \
            rw[p] = *(const float4*)&W [(size_t)(ty + 16 * p) * DD + (k0) + tx * 4]; \
        }                                                                     \
    }

    LOAD_TILES(0);

    for (int c = 0; c < NCHUNK; ++c) {
        __syncthreads();  // previous compute phase done; safe to overwrite LDS
        // transposed store: LDS is k-major [k][token/expert]
#pragma unroll
        for (int p = 0; p < 4; ++p) {
            const int col = ty + 16 * p;
            const int kk  = tx * 4;
            xs[(kk + 0) * LDSTR + col] = rx[p].x;
            xs[(kk + 1) * LDSTR + col] = rx[p].y;
            xs[(kk + 2) * LDSTR + col] = rx[p].z;
            xs[(kk + 3) * LDSTR + col] = rx[p].w;
            ws[(kk + 0) * LDSTR + col] = rw[p].x;
            ws[(kk + 1) * LDSTR + col] = rw[p].y;
            ws[(kk + 2) * LDSTR + col] = rw[p].z;
            ws[(kk + 3) * LDSTR + col] = rw[p].w;
        }
        __syncthreads();

        if (c + 1 < NCHUNK) {
            const int k0n = (c + 1) * BK;
            LOAD_TILES(k0n);
        }

#pragma unroll
        for (int k = 0; k < BK; ++k) {
            const float4 xv = *(const float4*)&xs[k * LDSTR + ty * 4];
            const float4 wv = *(const float4*)&ws[k * LDSTR + tx * 4];
            acc[0][0] += xv.x * wv.x; acc[0][1] += xv.x * wv.y;
            acc[0][2] += xv.x * wv.z; acc[0][3] += xv.x * wv.w;
            acc[1][0] += xv.y * wv.x; acc[1][1] += xv.y * wv.y;
            acc[1][2] += xv.y * wv.z; acc[1][3] += xv.y * wv.w;
            acc[2][0] += xv.z * wv.x; acc[2][1] += xv.z * wv.y;
            acc[2][2] += xv.z * wv.z; acc[2][3] += xv.z * wv.w;
            acc[3][0] += xv.w * wv.x; acc[3][1] += xv.w * wv.y;
            acc[3][2] += xv.w * wv.z; acc[3][3] += xv.w * wv.w;
        }
    }

    // -------- epilogue: logits -> LDS, per-token top-2 + softmax --------
    __syncthreads();
#pragma unroll
    for (int i = 0; i < 4; ++i)
#pragma unroll
        for (int j = 0; j < 4; ++j)
            logits[(ty * 4 + i) * (EE + 1) + (tx * 4 + j)] = acc[i][j] + bvals[j];
    __syncthreads();

    if (tid < TM) {
        const float* lrow = &logits[tid * (EE + 1)];
        float v1 = -INFINITY, v2 = -INFINITY;
        int   i1 = 0, i2 = 0;
        for (int e = 0; e < EE; ++e) {
            const float v = lrow[e];
            if (v > v1) { v2 = v1; i2 = i1; v1 = v; i1 = e; }
            else if (v > v2) { v2 = v; i2 = e; }
        }
        // softmax over [v1, v2] (v1 >= v2): g1 = 1/(1+e^{v2-v1})
        const float ed = expf(v2 - v1);
        const float inv = 1.f / (1.f + ed);
        const int tok = tBase + tid;
        out[tok * 2 + 0] = inv;
        out[tok * 2 + 1] = ed * inv;
        float* oidx = out + (size_t)2 * n_tokens;
        oidx[tok * 2 + 0] = (float)i1;
        oidx[tok * 2 + 1] = (float)i2;
    }
}

extern "C" void kernel_launch(void* const* d_in, const int* in_sizes, int n_in,
                              void* d_out, int out_size, void* d_ws, size_t ws_size,
                              hipStream_t stream) {
    const float* x = (const float*)d_in[0];
    const float* W = (const float*)d_in[1];
    const float* b = (const float*)d_in[2];
    float* out = (float*)d_out;

    const int n_tokens = in_sizes[0] / DD;      // 16384
    const int n_blocks = n_tokens / TM;         // 256

    router_kernel<<<n_blocks, THREADS, 0, stream>>>(x, W, b, out, n_tokens);
}